// Round 1
// baseline (876.720 us; speedup 1.0000x reference)
//
#include <hip/hip_runtime.h>

// ---------- types ----------
typedef __attribute__((ext_vector_type(8))) short s16x8;    // 8 bf16 (4 VGPR) MFMA frag
typedef __attribute__((ext_vector_type(4))) float f32x4;    // MFMA accumulator
typedef __attribute__((ext_vector_type(8))) unsigned short u16x8;
typedef __attribute__((ext_vector_type(4))) unsigned short u16x4;

// ---------- helpers ----------
__device__ __forceinline__ unsigned short f2b(float f) {   // f32 -> bf16 RNE
  unsigned u = __builtin_bit_cast(unsigned, f);
  u += 0x7fffu + ((u >> 16) & 1u);
  return (unsigned short)(u >> 16);
}
__device__ __forceinline__ float b2f(unsigned short h) {
  return __builtin_bit_cast(float, (unsigned)h << 16);
}
__device__ __forceinline__ void gl2lds16(const unsigned short* g, unsigned short* l) {
  __builtin_amdgcn_global_load_lds(
      (const __attribute__((address_space(1))) unsigned int*)g,
      (__attribute__((address_space(3))) unsigned int*)l, 16, 0, 0);
}

// ---------- fp32 -> bf16 convert (8 elems/thread, exact grid) ----------
__global__ __launch_bounds__(256)
void cvt_f32_bf16(const float* __restrict__ in, unsigned short* __restrict__ out) {
  size_t i = ((size_t)blockIdx.x * 256 + threadIdx.x) * 8;
  float4 a = *(const float4*)(in + i);
  float4 b = *(const float4*)(in + i + 4);
  u16x8 o;
  o[0] = f2b(a.x); o[1] = f2b(a.y); o[2] = f2b(a.z); o[3] = f2b(a.w);
  o[4] = f2b(b.x); o[5] = f2b(b.y); o[6] = f2b(b.z); o[7] = f2b(b.w);
  *(u16x8*)(out + i) = o;
}

// ---------- row sum of unnormalized P -> reciprocal ----------
__global__ __launch_bounds__(256)
void rowsum_recip(const unsigned short* __restrict__ P, float* __restrict__ rs) {
  const int row = blockIdx.x;
  const unsigned short* p = P + (size_t)row * 4096;
  const int t = threadIdx.x;
  float s = 0.f;
#pragma unroll
  for (int i = 0; i < 2; ++i) {
    u16x8 v = *(const u16x8*)(p + (size_t)(i * 256 + t) * 8);
#pragma unroll
    for (int j = 0; j < 8; ++j) s += b2f(v[j]);
  }
#pragma unroll
  for (int off = 32; off > 0; off >>= 1) s += __shfl_xor(s, off, 64);
  __shared__ float part[4];
  if ((t & 63) == 0) part[t >> 6] = s;
  __syncthreads();
  if (t == 0) rs[row] = 1.0f / (part[0] + part[1] + part[2] + part[3]);
}

// ---------- generic B^T GEMM: C[M,N] = A[M,K] * B[N,K]^T ----------
// A, B bf16 row-major (leading dim lda/ldb). 128x128 tile, BK=64, 4 waves.
// EPI 0: +bias[col], store bf16 C[row*ldc+col]
// EPI 1: +bias[col], store bf16 TRANSPOSED C[col*ldc+row]   (V -> V^T)
// EPI 2: exp2(acc*c1 + c2), store bf16 C[row*ldc+col]       (unnormalized P)
// EPI 3: acc * aux[row],    store f32  C[row*ldc+col]       (PV / rowsum)
#define BM 128
#define BN 128
#define BK 64

template<int EPI>
__global__ __launch_bounds__(256)
void gemm_bt(const unsigned short* __restrict__ A, int lda,
             const unsigned short* __restrict__ B, int ldb,
             void* __restrict__ Cv, int ldc,
             const float* __restrict__ aux,
             int K, float c1, float c2) {
  __shared__ __attribute__((aligned(16))) unsigned short smA[BM * BK];
  __shared__ __attribute__((aligned(16))) unsigned short smB[BN * BK];

  const int t = threadIdx.x;
  const int brow = blockIdx.x * BM;
  const int bcol = blockIdx.y * BN;

  // staging geometry: 256 thr x 16 B = 4 KB per issue; tile = 16 KB = 4 issues
  const int srow = t >> 3;           // 0..31
  const int scol = (t & 7) * 8;      // element col, multiple of 8 (16B aligned)
  const unsigned short* Ab = A + (size_t)(brow + srow) * lda + scol;
  const unsigned short* Bb = B + (size_t)(bcol + srow) * ldb + scol;

  const int lane = t & 63;
  const int w = t >> 6;
  const int wr = (w >> 1) * 64;      // wave's 64x64 sub-tile
  const int wc = (w & 1) * 64;
  const int fr = lane & 15;          // fragment row (A) / col (B)
  const int fk = (lane >> 4) * 8;    // fragment k offset
  const int rj = (lane >> 4) * 4;    // C/D row base

  f32x4 acc[4][4] = {};

  for (int k0 = 0; k0 < K; k0 += BK) {
#pragma unroll
    for (int i = 0; i < 4; ++i)
      gl2lds16(Ab + (size_t)(i * 32) * lda + k0, &smA[i * 2048 + t * 8]);
#pragma unroll
    for (int i = 0; i < 4; ++i)
      gl2lds16(Bb + (size_t)(i * 32) * ldb + k0, &smB[i * 2048 + t * 8]);
    __syncthreads();   // drains vmcnt -> staged tile visible

#pragma unroll
    for (int kk = 0; kk < BK; kk += 32) {
      s16x8 af[4], bf[4];
#pragma unroll
      for (int m = 0; m < 4; ++m)
        af[m] = *(const s16x8*)&smA[(wr + m * 16 + fr) * BK + kk + fk];
#pragma unroll
      for (int n = 0; n < 4; ++n)
        bf[n] = *(const s16x8*)&smB[(wc + n * 16 + fr) * BK + kk + fk];
#pragma unroll
      for (int m = 0; m < 4; ++m)
#pragma unroll
        for (int n = 0; n < 4; ++n)
          acc[m][n] = __builtin_amdgcn_mfma_f32_16x16x32_bf16(af[m], bf[n], acc[m][n], 0, 0, 0);
    }
    __syncthreads();   // everyone done reading before next stage overwrites
  }

  (void)c1; (void)c2;
  if constexpr (EPI == 0 || EPI == 2) {
    unsigned short* O = (unsigned short*)Cv;
#pragma unroll
    for (int n = 0; n < 4; ++n) {
      const int col = bcol + wc + n * 16 + fr;
      const float bias = (EPI == 0) ? aux[col] : 0.f;
#pragma unroll
      for (int m = 0; m < 4; ++m) {
        const int r0 = brow + wr + m * 16 + rj;
#pragma unroll
        for (int j = 0; j < 4; ++j) {
          float v = acc[m][n][j];
          if constexpr (EPI == 0) v += bias;
          else v = exp2f(v * c1 + c2);
          O[(size_t)(r0 + j) * ldc + col] = f2b(v);
        }
      }
    }
  } else if constexpr (EPI == 1) {
    unsigned short* O = (unsigned short*)Cv;
#pragma unroll
    for (int n = 0; n < 4; ++n) {
      const int col = bcol + wc + n * 16 + fr;
      const float bias = aux[col];
#pragma unroll
      for (int m = 0; m < 4; ++m) {
        const int r0 = brow + wr + m * 16 + rj;
        u16x4 pk;
#pragma unroll
        for (int j = 0; j < 4; ++j) pk[j] = f2b(acc[m][n][j] + bias);
        *(u16x4*)(O + (size_t)col * ldc + r0) = pk;   // transposed, 8B packed
      }
    }
  } else {  // EPI == 3
    float* O = (float*)Cv;
#pragma unroll
    for (int m = 0; m < 4; ++m) {
      const int r0 = brow + wr + m * 16 + rj;
      float inv[4];
#pragma unroll
      for (int j = 0; j < 4; ++j) inv[j] = aux[r0 + j];
#pragma unroll
      for (int n = 0; n < 4; ++n) {
        const int col = bcol + wc + n * 16 + fr;
#pragma unroll
        for (int j = 0; j < 4; ++j)
          O[(size_t)(r0 + j) * ldc + col] = acc[m][n][j] * inv[j];
      }
    }
  }
}

// ---------- launch ----------
extern "C" void kernel_launch(void* const* d_in, const int* in_sizes, int n_in,
                              void* d_out, int out_size, void* d_ws, size_t ws_size,
                              hipStream_t stream) {
  const float* x  = (const float*)d_in[0];
  const float* Wq = (const float*)d_in[1];
  const float* bq = (const float*)d_in[2];
  const float* Wk = (const float*)d_in[3];
  const float* bk = (const float*)d_in[4];
  const float* Wv = (const float*)d_in[5];
  const float* bv = (const float*)d_in[6];
  float* out = (float*)d_out;

  // B=4, S=4096, D=1024
  const size_t SD = (size_t)16384 * 1024;       // 16.7M elems
  unsigned short* xb  = (unsigned short*)d_ws;  // x in bf16        [16384][1024]
  unsigned short* wqb = xb  + SD;               // Wq bf16          [1024][1024]
  unsigned short* wkb = wqb + (size_t)1024 * 1024;
  unsigned short* wvb = wkb + (size_t)1024 * 1024;
  unsigned short* qb  = wvb + (size_t)1024 * 1024;  // q bf16       [16384][1024]
  unsigned short* kb  = qb  + SD;                   // k bf16       [16384][1024]
  unsigned short* vt  = kb  + SD;                   // v^T bf16     [1024][16384]
  unsigned short* Pb  = vt  + SD;                   // per-batch P  [4096][4096]
  float* rs = (float*)(Pb + (size_t)4096 * 4096);   // per-batch 1/rowsum [4096]

  // convert inputs to bf16
  cvt_f32_bf16<<<8192, 256, 0, stream>>>(x, xb);      // 16777216 / 2048
  cvt_f32_bf16<<<512, 256, 0, stream>>>(Wq, wqb);     // 1048576 / 2048
  cvt_f32_bf16<<<512, 256, 0, stream>>>(Wk, wkb);
  cvt_f32_bf16<<<512, 256, 0, stream>>>(Wv, wvb);

  // QKV projections: [16384,1024] x [1024,1024]^T
  gemm_bt<0><<<dim3(128, 8), 256, 0, stream>>>(xb, 1024, wqb, 1024, qb, 1024, bq, 1024, 0.f, 0.f);
  gemm_bt<0><<<dim3(128, 8), 256, 0, stream>>>(xb, 1024, wkb, 1024, kb, 1024, bk, 1024, 0.f, 0.f);
  gemm_bt<1><<<dim3(128, 8), 256, 0, stream>>>(xb, 1024, wvb, 1024, vt, 16384, bv, 1024, 0.f, 0.f);

  // attention per batch: P = exp(q k^T / 32 - 16);  out = (P v) / rowsum(P)
  const float LOG2E = 1.4426950408889634f;
  const float c1 = LOG2E / 32.f;     // acc * (1/32) in log2 domain
  const float c2 = -16.f * LOG2E;    // fixed shift (softmax shift-invariant)
  for (int b = 0; b < 4; ++b) {
    const size_t qo = (size_t)b * 4096 * 1024;
    gemm_bt<2><<<dim3(32, 32), 256, 0, stream>>>(qb + qo, 1024, kb + qo, 1024,
                                                 Pb, 4096, nullptr, 1024, c1, c2);
    rowsum_recip<<<4096, 256, 0, stream>>>(Pb, rs);
    gemm_bt<3><<<dim3(32, 8), 256, 0, stream>>>(Pb, 4096, vt + (size_t)b * 4096, 16384,
                                                out + qo, 1024, rs, 4096, 0.f, 0.f);
  }
}

// Round 2
// 859.744 us; speedup vs baseline: 1.0197x; 1.0197x over previous
//
#include <hip/hip_runtime.h>

// ---------- types ----------
typedef __attribute__((ext_vector_type(8))) short s16x8;    // 8 bf16 MFMA frag
typedef __attribute__((ext_vector_type(4))) float f32x4;    // MFMA accumulator
typedef __attribute__((ext_vector_type(8))) unsigned short u16x8;
typedef __attribute__((ext_vector_type(4))) unsigned short u16x4;

// ---------- helpers ----------
__device__ __forceinline__ unsigned short f2b(float f) {   // f32 -> bf16 RNE
  unsigned u = __builtin_bit_cast(unsigned, f);
  u += 0x7fffu + ((u >> 16) & 1u);
  return (unsigned short)(u >> 16);
}
__device__ __forceinline__ float b2f(unsigned short h) {
  return __builtin_bit_cast(float, (unsigned)h << 16);
}
__device__ __forceinline__ void gl2lds16(const unsigned short* g, unsigned short* l) {
  __builtin_amdgcn_global_load_lds(
      (const __attribute__((address_space(1))) unsigned int*)g,
      (__attribute__((address_space(3))) unsigned int*)l, 16, 0, 0);
}

// ---------- fp32 -> bf16 convert ----------
__global__ __launch_bounds__(256)
void cvt_f32_bf16(const float* __restrict__ in, unsigned short* __restrict__ out) {
  size_t i = ((size_t)blockIdx.x * 256 + threadIdx.x) * 8;
  float4 a = *(const float4*)(in + i);
  float4 b = *(const float4*)(in + i + 4);
  u16x8 o;
  o[0] = f2b(a.x); o[1] = f2b(a.y); o[2] = f2b(a.z); o[3] = f2b(a.w);
  o[4] = f2b(b.x); o[5] = f2b(b.y); o[6] = f2b(b.z); o[7] = f2b(b.w);
  *(u16x8*)(out + i) = o;
}

// ---------- row sum of unnormalized P -> reciprocal ----------
__global__ __launch_bounds__(256)
void rowsum_recip(const unsigned short* __restrict__ P, float* __restrict__ rs) {
  const int row = blockIdx.x;
  const unsigned short* p = P + (size_t)row * 4096;
  const int t = threadIdx.x;
  float s = 0.f;
#pragma unroll
  for (int i = 0; i < 2; ++i) {
    u16x8 v = *(const u16x8*)(p + (size_t)(i * 256 + t) * 8);
#pragma unroll
    for (int j = 0; j < 8; ++j) s += b2f(v[j]);
  }
#pragma unroll
  for (int off = 32; off > 0; off >>= 1) s += __shfl_xor(s, off, 64);
  __shared__ float part[4];
  if ((t & 63) == 0) part[t >> 6] = s;
  __syncthreads();
  if (t == 0) rs[row] = 1.0f / (part[0] + part[1] + part[2] + part[3]);
}

// ============================================================================
// 256x256 GEMM, BK=32, 512 threads (8 waves as 2Mx4N), 4-slot LDS ring,
// counted vmcnt(8) gates (2 K-tiles always in flight), T2 swizzle, T5 setprio,
// T1 XCD swizzle.  C[M,N] = A[M,K] * B[N,K]^T, batched over blockIdx.z.
// EPI 0: +bias[col] -> bf16 C;  EPI 1: +bias[col] -> bf16 C^T (ldc = M-stride)
// EPI 2: exp2(acc*c1+c2) -> bf16 C;  EPI 3: acc*aux[row] -> f32 C
// ============================================================================
template<int EPI>
__global__ __launch_bounds__(512, 2)
void gemm256(const unsigned short* __restrict__ A, int lda, size_t aStrZ,
             const unsigned short* __restrict__ B, int ldb, size_t bStrZ,
             void* __restrict__ Cv, int ldc, size_t cStrZ,
             const float* __restrict__ aux, size_t auxStrZ,
             int K, float c1, float c2) {
  __shared__ __attribute__((aligned(16))) unsigned short smA[4][256 * 32];
  __shared__ __attribute__((aligned(16))) unsigned short smB[4][256 * 32];

  const int t = threadIdx.x;
  const int z = blockIdx.z;
  A += (size_t)z * aStrZ;
  B += (size_t)z * bStrZ;
  const float* auxz = aux + (size_t)z * auxStrZ;

  // T1: bijective XCD swizzle (all grids have nwg % 8 == 0)
  const int gx = gridDim.x;
  int lin = blockIdx.y * gx + blockIdx.x;
  const int cpx = (gx * gridDim.y) >> 3;
  lin = (lin & 7) * cpx + (lin >> 3);
  const int brow = (lin % gx) * 256;
  const int bcol = (lin / gx) * 256;

  const int lane = t & 63, w = t >> 6;
  const int wm = w >> 2, wn = w & 3;        // 2 x 4 wave grid
  const int fr = lane & 15, c0 = lane >> 4;
  // T2 swizzle: 16B-slot s holds global col-slot (s ^ ((row>>1)&3))
  const int swz8 = ((c0 ^ ((fr >> 1) & 3)) << 3);           // ds_read col elems
  // staging per-thread constants (line = 128 rows x 32 cols, 64B/row)
  const int s_row  = t >> 2;                                 // 0..127
  const int s_colE = (((t & 3) ^ ((t >> 3) & 3)) << 3);      // pre-swizzled src col
  const int s_dstE = (t >> 2) * 32 + (t & 3) * 8;            // linear LDS dest

  const unsigned short* Ar0 = A + (size_t)(brow + s_row) * lda + s_colE;
  const unsigned short* Ar1 = Ar0 + (size_t)128 * lda;
  const unsigned short* Br0 = B + (size_t)(bcol + s_row) * ldb + s_colE;
  const unsigned short* Br1 = Br0 + (size_t)128 * ldb;

  const int NT = K >> 5;
  auto STAGE = [&](int tt) {
    const int tc = tt < NT ? tt : NT - 1;   // tail clamp: lands in a dead slot
    const int slot = tt & 3;
    const int k0 = tc * 32;
    gl2lds16(Ar0 + k0, &smA[slot][s_dstE]);
    gl2lds16(Ar1 + k0, &smA[slot][4096 + s_dstE]);
    gl2lds16(Br0 + k0, &smB[slot][s_dstE]);
    gl2lds16(Br1 + k0, &smB[slot][4096 + s_dstE]);
  };

  STAGE(0); STAGE(1); STAGE(2);
  asm volatile("s_waitcnt vmcnt(8)" ::: "memory");   // tile 0 landed
  __builtin_amdgcn_s_barrier();
  __builtin_amdgcn_sched_barrier(0);

  f32x4 acc[8][4] = {};
  const int arBase = wm * 128;
  const int brBase = wn * 64;

  for (int tt = 0; tt < NT; ++tt) {
    const int slot = tt & 3;
    STAGE(tt + 3);                                   // into slot (tt-1)&3: dead
    const unsigned short* sa = &smA[slot][0];
    const unsigned short* sb = &smB[slot][0];
    s16x8 af[8], bf[4];
#pragma unroll
    for (int m = 0; m < 8; ++m)
      af[m] = *(const s16x8*)&sa[(arBase + m * 16 + fr) * 32 + swz8];
#pragma unroll
    for (int n = 0; n < 4; ++n)
      bf[n] = *(const s16x8*)&sb[(brBase + n * 16 + fr) * 32 + swz8];
    __builtin_amdgcn_s_setprio(1);
#pragma unroll
    for (int m = 0; m < 8; ++m)
#pragma unroll
      for (int n = 0; n < 4; ++n)
        acc[m][n] = __builtin_amdgcn_mfma_f32_16x16x32_bf16(af[m], bf[n], acc[m][n], 0, 0, 0);
    __builtin_amdgcn_s_setprio(0);
    asm volatile("s_waitcnt vmcnt(8)" ::: "memory"); // tile tt+1 landed; 2 tiles fly
    __builtin_amdgcn_s_barrier();
    __builtin_amdgcn_sched_barrier(0);
  }

  // ---- epilogue ----
  const int rj = (lane >> 4) * 4;
  if constexpr (EPI == 0 || EPI == 2) {
    unsigned short* O = (unsigned short*)Cv + (size_t)z * cStrZ;
#pragma unroll
    for (int n = 0; n < 4; ++n) {
      const int col = bcol + brBase + n * 16 + fr;
      const float bias = (EPI == 0) ? auxz[col] : 0.f;
#pragma unroll
      for (int m = 0; m < 8; ++m) {
        const int r0 = brow + arBase + m * 16 + rj;
#pragma unroll
        for (int j = 0; j < 4; ++j) {
          float v = acc[m][n][j];
          if constexpr (EPI == 0) v += bias;
          else v = exp2f(v * c1 + c2);
          O[(size_t)(r0 + j) * ldc + col] = f2b(v);
        }
      }
    }
  } else if constexpr (EPI == 1) {
    unsigned short* O = (unsigned short*)Cv + (size_t)z * cStrZ;
#pragma unroll
    for (int n = 0; n < 4; ++n) {
      const int col = bcol + brBase + n * 16 + fr;
      const float bias = auxz[col];
#pragma unroll
      for (int m = 0; m < 8; ++m) {
        const int r0 = brow + arBase + m * 16 + rj;
        u16x4 pk;
#pragma unroll
        for (int j = 0; j < 4; ++j) pk[j] = f2b(acc[m][n][j] + bias);
        *(u16x4*)(O + (size_t)col * ldc + r0) = pk;   // transposed store
      }
    }
  } else {  // EPI == 3
    float* O = (float*)Cv + (size_t)z * cStrZ;
#pragma unroll
    for (int m = 0; m < 8; ++m) {
      const int r0 = brow + arBase + m * 16 + rj;
      float inv[4];
#pragma unroll
      for (int j = 0; j < 4; ++j) inv[j] = auxz[r0 + j];
#pragma unroll
      for (int n = 0; n < 4; ++n) {
        const int col = bcol + brBase + n * 16 + fr;
#pragma unroll
        for (int j = 0; j < 4; ++j)
          O[(size_t)(r0 + j) * ldc + col] = acc[m][n][j] * inv[j];
      }
    }
  }
}

// ============================================================================
// Fallback 128x128 GEMM (round-1 structure), only EPI 3 used (per-batch PV).
// ============================================================================
template<int EPI>
__global__ __launch_bounds__(256)
void gemm_bt(const unsigned short* __restrict__ A, int lda,
             const unsigned short* __restrict__ B, int ldb,
             void* __restrict__ Cv, int ldc,
             const float* __restrict__ aux,
             int K) {
  __shared__ __attribute__((aligned(16))) unsigned short smA[128 * 64];
  __shared__ __attribute__((aligned(16))) unsigned short smB[128 * 64];
  const int t = threadIdx.x;
  const int brow = blockIdx.x * 128;
  const int bcol = blockIdx.y * 128;
  const int srow = t >> 3;
  const int scol = (t & 7) * 8;
  const unsigned short* Ab = A + (size_t)(brow + srow) * lda + scol;
  const unsigned short* Bb = B + (size_t)(bcol + srow) * ldb + scol;
  const int lane = t & 63;
  const int w = t >> 6;
  const int wr = (w >> 1) * 64;
  const int wc = (w & 1) * 64;
  const int fr = lane & 15;
  const int fk = (lane >> 4) * 8;
  const int rj = (lane >> 4) * 4;
  f32x4 acc[4][4] = {};
  for (int k0 = 0; k0 < K; k0 += 64) {
#pragma unroll
    for (int i = 0; i < 4; ++i)
      gl2lds16(Ab + (size_t)(i * 32) * lda + k0, &smA[i * 2048 + t * 8]);
#pragma unroll
    for (int i = 0; i < 4; ++i)
      gl2lds16(Bb + (size_t)(i * 32) * ldb + k0, &smB[i * 2048 + t * 8]);
    __syncthreads();
#pragma unroll
    for (int kk = 0; kk < 64; kk += 32) {
      s16x8 af[4], bf[4];
#pragma unroll
      for (int m = 0; m < 4; ++m) af[m] = *(const s16x8*)&smA[(wr + m * 16 + fr) * 64 + kk + fk];
#pragma unroll
      for (int n = 0; n < 4; ++n) bf[n] = *(const s16x8*)&smB[(wc + n * 16 + fr) * 64 + kk + fk];
#pragma unroll
      for (int m = 0; m < 4; ++m)
#pragma unroll
        for (int n = 0; n < 4; ++n)
          acc[m][n] = __builtin_amdgcn_mfma_f32_16x16x32_bf16(af[m], bf[n], acc[m][n], 0, 0, 0);
    }
    __syncthreads();
  }
  float* O = (float*)Cv;
#pragma unroll
  for (int m = 0; m < 4; ++m) {
    const int r0 = brow + wr + m * 16 + rj;
    float inv[4];
#pragma unroll
    for (int j = 0; j < 4; ++j) inv[j] = aux[r0 + j];
#pragma unroll
    for (int n = 0; n < 4; ++n) {
      const int col = bcol + wc + n * 16 + fr;
#pragma unroll
      for (int j = 0; j < 4; ++j)
        O[(size_t)(r0 + j) * ldc + col] = acc[m][n][j] * inv[j];
    }
  }
}

// ---------- launch ----------
extern "C" void kernel_launch(void* const* d_in, const int* in_sizes, int n_in,
                              void* d_out, int out_size, void* d_ws, size_t ws_size,
                              hipStream_t stream) {
  const float* x  = (const float*)d_in[0];
  const float* Wq = (const float*)d_in[1];
  const float* bq = (const float*)d_in[2];
  const float* Wk = (const float*)d_in[3];
  const float* bk = (const float*)d_in[4];
  const float* Wv = (const float*)d_in[5];
  const float* bv = (const float*)d_in[6];
  float* out = (float*)d_out;

  // B=4, S=4096, D=1024
  const size_t SD = (size_t)16384 * 1024;
  const size_t SS = (size_t)4096 * 4096;
  unsigned short* xb  = (unsigned short*)d_ws;
  unsigned short* wqb = xb  + SD;
  unsigned short* wkb = wqb + (size_t)1024 * 1024;
  unsigned short* wvb = wkb + (size_t)1024 * 1024;
  unsigned short* qb  = wvb + (size_t)1024 * 1024;
  unsigned short* kb  = qb  + SD;
  unsigned short* vt  = kb  + SD;       // v^T  [1024][16384]
  unsigned short* Pa  = vt  + SD;       // P    [4][4096][4096] (batched) or [4096][4096]

  const size_t needBatched = (SD + 3 * (size_t)1048576 + 3 * SD + 4 * SS) * 2 + 16384 * 4;
  const bool batched = ws_size >= needBatched;
  float* rs = (float*)(Pa + (batched ? 4 * SS : SS));

  cvt_f32_bf16<<<8192, 256, 0, stream>>>(x, xb);
  cvt_f32_bf16<<<512, 256, 0, stream>>>(Wq, wqb);
  cvt_f32_bf16<<<512, 256, 0, stream>>>(Wk, wkb);
  cvt_f32_bf16<<<512, 256, 0, stream>>>(Wv, wvb);

  // projections: [16384,1024] x [1024,1024]^T  (256 blocks each)
  gemm256<0><<<dim3(64, 4, 1), 512, 0, stream>>>(xb, 1024, 0, wqb, 1024, 0,
                                                 qb, 1024, 0, bq, 0, 1024, 0.f, 0.f);
  gemm256<0><<<dim3(64, 4, 1), 512, 0, stream>>>(xb, 1024, 0, wkb, 1024, 0,
                                                 kb, 1024, 0, bk, 0, 1024, 0.f, 0.f);
  gemm256<1><<<dim3(64, 4, 1), 512, 0, stream>>>(xb, 1024, 0, wvb, 1024, 0,
                                                 vt, 16384, 0, bv, 0, 1024, 0.f, 0.f);

  const float LOG2E = 1.4426950408889634f;
  const float c1 = LOG2E / 32.f;     // scores * (1/sqrt(D)) in log2 domain
  const float c2 = -16.f * LOG2E;    // fixed shift (softmax is shift-invariant;
                                     // |scores/32| <= 32 so no overflow)
  if (batched) {
    gemm256<2><<<dim3(16, 16, 4), 512, 0, stream>>>(
        qb, 1024, SD / 4, kb, 1024, SD / 4, Pa, 4096, SS, nullptr, 0, 1024, c1, c2);
    rowsum_recip<<<16384, 256, 0, stream>>>(Pa, rs);
    gemm256<3><<<dim3(16, 4, 4), 512, 0, stream>>>(
        Pa, 4096, SS, vt, 16384, 4096, out, 1024, SD / 4, rs, 4096, 4096, 0.f, 0.f);
  } else {
    for (int b = 0; b < 4; ++b) {
      const size_t qo = (size_t)b * 4096 * 1024;
      gemm256<2><<<dim3(16, 16, 1), 512, 0, stream>>>(
          qb + qo, 1024, 0, kb + qo, 1024, 0, Pa, 4096, 0, nullptr, 0, 1024, c1, c2);
      rowsum_recip<<<4096, 256, 0, stream>>>(Pa, rs);
      gemm_bt<3><<<dim3(32, 8), 256, 0, stream>>>(Pa, 4096, vt + (size_t)b * 4096, 16384,
                                                  out + qo, 1024, rs, 4096);
    }
  }
}

// Round 4
// 685.594 us; speedup vs baseline: 1.2788x; 1.2540x over previous
//
#include <hip/hip_runtime.h>

// ---------- types ----------
typedef __attribute__((ext_vector_type(8))) short s16x8;    // 8 bf16 MFMA frag
typedef __attribute__((ext_vector_type(4))) float f32x4;    // MFMA accumulator
typedef __attribute__((ext_vector_type(8))) unsigned short u16x8;
typedef __attribute__((ext_vector_type(4))) unsigned short u16x4;

// ---------- helpers ----------
__device__ __forceinline__ unsigned short f2b(float f) {   // f32 -> bf16 RNE
  unsigned u = __builtin_bit_cast(unsigned, f);
  u += 0x7fffu + ((u >> 16) & 1u);
  return (unsigned short)(u >> 16);
}
__device__ __forceinline__ void gl2lds16(const unsigned short* g, unsigned short* l) {
  __builtin_amdgcn_global_load_lds(
      (const __attribute__((address_space(1))) unsigned int*)g,
      (__attribute__((address_space(3))) unsigned int*)l, 16, 0, 0);
}

// ---------- fp32 -> bf16 convert ----------
__global__ __launch_bounds__(256)
void cvt_f32_bf16(const float* __restrict__ in, unsigned short* __restrict__ out) {
  size_t i = ((size_t)blockIdx.x * 256 + threadIdx.x) * 8;
  float4 a = *(const float4*)(in + i);
  float4 b = *(const float4*)(in + i + 4);
  u16x8 o;
  o[0] = f2b(a.x); o[1] = f2b(a.y); o[2] = f2b(a.z); o[3] = f2b(a.w);
  o[4] = f2b(b.x); o[5] = f2b(b.y); o[6] = f2b(b.z); o[7] = f2b(b.w);
  *(u16x8*)(out + i) = o;
}

// ---------- 1/rowsum from per-tile partials: rs[r] = 1/sum(partial[r][0..63]) ----------
__global__ __launch_bounds__(256)
void rs_recip(const float* __restrict__ partial, float* __restrict__ rs) {
  int r = blockIdx.x * 256 + threadIdx.x;       // 8192 rows (2 batches)
  const float* p = partial + (size_t)r * 64;
  float s = 0.f;
#pragma unroll
  for (int i = 0; i < 16; ++i) {
    f32x4 v = *(const f32x4*)(p + i * 4);
    s += v[0] + v[1] + v[2] + v[3];
  }
  rs[r] = 1.0f / s;
}

// ============================================================================
// TMx256 GEMM, BK=32, 512 threads (8 waves, 2Mx4N), 4-slot LDS ring,
// counted vmcnt (2 K-tiles in flight), T2 swizzle, T5 setprio, T1 XCD swizzle.
// C[M,N] = A[M,K] * B[N,K]^T, batched over blockIdx.z.
// EPI 0: +bias[col] -> bf16 C (coalesced via LDS bounce)
// EPI 1: +bias[col] -> bf16 C^T (ldc = M-stride of C^T)
// EPI 2: exp2(acc*c1+c2) -> bf16 C (bounce) + per-row partial sums
// EPI 3: acc*aux[row] -> f32 C (bounce)
// ============================================================================
template<int EPI, int TM>
__global__ __launch_bounds__(512, 2)
void gemm256(const unsigned short* __restrict__ A, int lda, size_t aStrZ,
             const unsigned short* __restrict__ B, int ldb, size_t bStrZ,
             void* __restrict__ Cv, int ldc, size_t cStrZ,
             const float* __restrict__ aux, size_t auxStrZ,
             int K, float c1, float c2, float* __restrict__ partial) {
  constexpr int WM = TM / 32;                       // acc m-frags per wave
  __shared__ __attribute__((aligned(16))) unsigned short smA[4][TM * 32];
  __shared__ __attribute__((aligned(16))) unsigned short smB[4][256 * 32];

  const int t = threadIdx.x;
  const int z = blockIdx.z;
  A += (size_t)z * aStrZ;
  B += (size_t)z * bStrZ;
  const float* auxz = aux + (size_t)z * auxStrZ;

  // T1: bijective XCD swizzle (nwg per z always % 8 == 0 here)
  const int gx = gridDim.x;
  int lin = blockIdx.y * gx + blockIdx.x;
  const int cpx = (gx * gridDim.y) >> 3;
  lin = (lin & 7) * cpx + (lin >> 3);
  const int brow = (lin % gx) * TM;
  const int bcol = (lin / gx) * 256;

  const int lane = t & 63, w = t >> 6;
  const int wm = w >> 2, wn = w & 3;                // 2 x 4 wave grid
  const int fr = lane & 15, c0 = lane >> 4;
  const int swz8 = ((c0 ^ ((fr >> 1) & 3)) << 3);   // T2 swizzled k-slot
  // staging: line = 128 rows x 32 cols; pre-swizzled global col, linear LDS dst
  const int s_row  = t >> 2;                        // 0..127
  const int s_colE = (((t & 3) ^ ((t >> 3) & 3)) << 3);
  const int s_dstE = (t >> 2) * 32 + (t & 3) * 8;

  const unsigned short* Ar0 = A + (size_t)(brow + s_row) * lda + s_colE;
  const unsigned short* Ar1 = Ar0 + (size_t)128 * lda;   // used only if TM==256
  const unsigned short* Br0 = B + (size_t)(bcol + s_row) * ldb + s_colE;
  const unsigned short* Br1 = Br0 + (size_t)128 * ldb;

  const int NT = K >> 5;
  auto STAGE = [&](int tt) {
    const int tc = tt < NT ? tt : NT - 1;   // tail clamp (dead slot, in-bounds)
    const int slot = tt & 3;
    const int k0 = tc * 32;
    gl2lds16(Ar0 + k0, &smA[slot][s_dstE]);
    if constexpr (TM == 256) gl2lds16(Ar1 + k0, &smA[slot][4096 + s_dstE]);
    gl2lds16(Br0 + k0, &smB[slot][s_dstE]);
    gl2lds16(Br1 + k0, &smB[slot][4096 + s_dstE]);
  };
  auto WAITV = [&]() {   // 2 K-tiles always in flight, never drain to 0
    if constexpr (TM == 256) asm volatile("s_waitcnt vmcnt(8)" ::: "memory");
    else                     asm volatile("s_waitcnt vmcnt(6)" ::: "memory");
  };

  STAGE(0); STAGE(1); STAGE(2);
  WAITV();                                  // tile 0 landed
  __builtin_amdgcn_s_barrier();
  __builtin_amdgcn_sched_barrier(0);

  f32x4 acc[WM][4] = {};
  const int arBase = wm * (TM / 2);
  const int brBase = wn * 64;

  for (int tt = 0; tt < NT; ++tt) {
    const int slot = tt & 3;
    STAGE(tt + 3);                          // into slot (tt-1)&3: read-complete
    const unsigned short* sa = &smA[slot][0];
    const unsigned short* sb = &smB[slot][0];
    s16x8 af[WM], bf[4];
#pragma unroll
    for (int m = 0; m < WM; ++m)
      af[m] = *(const s16x8*)&sa[(arBase + m * 16 + fr) * 32 + swz8];
#pragma unroll
    for (int n = 0; n < 4; ++n)
      bf[n] = *(const s16x8*)&sb[(brBase + n * 16 + fr) * 32 + swz8];
    __builtin_amdgcn_s_setprio(1);
#pragma unroll
    for (int m = 0; m < WM; ++m)
#pragma unroll
      for (int n = 0; n < 4; ++n)
        acc[m][n] = __builtin_amdgcn_mfma_f32_16x16x32_bf16(af[m], bf[n], acc[m][n], 0, 0, 0);
    __builtin_amdgcn_s_setprio(0);
    WAITV();                                // tile tt+1 landed
    __builtin_amdgcn_s_barrier();
    __builtin_amdgcn_sched_barrier(0);
  }

  // ---- epilogue: drain tail DMA, then LDS is free for bounce buffers ----
  asm volatile("s_waitcnt vmcnt(0)" ::: "memory");
  __builtin_amdgcn_s_barrier();

  const int rj = (lane >> 4) * 4;
  // per-wave 16 x 272B bounce region (272B row = 68 floats: bank-balanced)
  float* lb = (float*)((char*)(TM == 256 ? (void*)&smA[0][0] : (void*)&smB[0][0])
                       + w * (16 * 272));

  if constexpr (EPI == 0 || EPI == 2) {
    unsigned short* O = (unsigned short*)Cv + (size_t)z * cStrZ;
    float bias[4];
    if constexpr (EPI == 0) {
#pragma unroll
      for (int n = 0; n < 4; ++n) bias[n] = auxz[bcol + brBase + n * 16 + fr];
    }
    const int r8 = lane >> 3, cc8 = lane & 7;
#pragma unroll
    for (int m = 0; m < WM; ++m) {
      float e[4][4];
#pragma unroll
      for (int n = 0; n < 4; ++n)
#pragma unroll
        for (int j = 0; j < 4; ++j) {
          float v = acc[m][n][j];
          if constexpr (EPI == 0) v += bias[n];
          else v = exp2f(v * c1 + c2);
          e[n][j] = v;
        }
      if constexpr (EPI == 2) {     // fused row-sum partial (this wave's 64 cols)
#pragma unroll
        for (int j = 0; j < 4; ++j) {
          float s = e[0][j] + e[1][j] + e[2][j] + e[3][j];
          s += __shfl_xor(s, 1); s += __shfl_xor(s, 2);
          s += __shfl_xor(s, 4); s += __shfl_xor(s, 8);
          if (fr == 0) {
            const int row = brow + arBase + m * 16 + rj + j;
            partial[((size_t)z * 4096 + row) * 64 + ((bcol >> 8) << 2) + wn] = s;
          }
        }
      }
#pragma unroll
      for (int n = 0; n < 4; ++n)
#pragma unroll
        for (int j = 0; j < 4; ++j)
          lb[(rj + j) * 68 + n * 16 + fr] = e[n][j];
      asm volatile("s_waitcnt lgkmcnt(0)" ::: "memory");
      __builtin_amdgcn_sched_barrier(0);
      const int rowb = brow + arBase + m * 16;
      const int colb = bcol + brBase + cc8 * 8;
#pragma unroll
      for (int h = 0; h < 2; ++h) {
        const int r = r8 + h * 8;
        f32x4 v0 = *(const f32x4*)&lb[r * 68 + cc8 * 8];
        f32x4 v1 = *(const f32x4*)&lb[r * 68 + cc8 * 8 + 4];
        u16x8 o;
        o[0] = f2b(v0[0]); o[1] = f2b(v0[1]); o[2] = f2b(v0[2]); o[3] = f2b(v0[3]);
        o[4] = f2b(v1[0]); o[5] = f2b(v1[1]); o[6] = f2b(v1[2]); o[7] = f2b(v1[3]);
        *(u16x8*)&O[(size_t)(rowb + r) * ldc + colb] = o;
      }
      asm volatile("" ::: "memory");   // keep m-iterations ordered on lb reuse
    }
  } else if constexpr (EPI == 1) {     // transposed bf16 store (V -> V^T), TM=256
    unsigned short* O = (unsigned short*)Cv + (size_t)z * cStrZ;
#pragma unroll
    for (int n = 0; n < 4; ++n) {
      const int col = bcol + brBase + n * 16 + fr;
      const float bias = auxz[col];
#pragma unroll
      for (int m = 0; m < WM; ++m) {
        const int r0 = brow + arBase + m * 16 + rj;
        u16x4 pk;
#pragma unroll
        for (int j = 0; j < 4; ++j) pk[j] = f2b(acc[m][n][j] + bias);
        *(u16x4*)(O + (size_t)col * ldc + r0) = pk;
      }
    }
  } else {                              // EPI 3: f32 out, coalesced bounce
    float* O = (float*)Cv + (size_t)z * cStrZ;
    const int r4 = lane >> 4, c16 = lane & 15;
#pragma unroll
    for (int m = 0; m < WM; ++m) {
      const int rowb = brow + arBase + m * 16;
      float e[4][4];
#pragma unroll
      for (int j = 0; j < 4; ++j) {
        const float inv = auxz[rowb + rj + j];
#pragma unroll
        for (int n = 0; n < 4; ++n) e[n][j] = acc[m][n][j] * inv;
      }
#pragma unroll
      for (int n = 0; n < 4; ++n)
#pragma unroll
        for (int j = 0; j < 4; ++j)
          lb[(rj + j) * 68 + n * 16 + fr] = e[n][j];
      asm volatile("s_waitcnt lgkmcnt(0)" ::: "memory");
      __builtin_amdgcn_sched_barrier(0);
#pragma unroll
      for (int g = 0; g < 4; ++g) {
        const int r = g * 4 + r4;
        f32x4 v = *(const f32x4*)&lb[r * 68 + c16 * 4];
        *(f32x4*)&O[(size_t)(rowb + r) * ldc + bcol + brBase + c16 * 4] = v;
      }
      asm volatile("" ::: "memory");
    }
  }
}

// ---------- launch ----------
extern "C" void kernel_launch(void* const* d_in, const int* in_sizes, int n_in,
                              void* d_out, int out_size, void* d_ws, size_t ws_size,
                              hipStream_t stream) {
  const float* x  = (const float*)d_in[0];
  const float* Wq = (const float*)d_in[1];
  const float* bq = (const float*)d_in[2];
  const float* Wk = (const float*)d_in[3];
  const float* bk = (const float*)d_in[4];
  const float* Wv = (const float*)d_in[5];
  const float* bv = (const float*)d_in[6];
  float* out = (float*)d_out;

  // B=4, S=4096, D=1024.  Layout (elements of u16); SD == SS == 16.78M:
  //   [qb SD][kb SD][vt SD][P0 SD][P1 SD][partial 2MB f32][rs 32KB f32]
  //   xb/weights aliased at P0 (dead after projections; stream-ordered).
  // Total 170 MB <= known ws_size (>=174 MB, proven by round-1 layout passing).
  const size_t SD = (size_t)16384 * 1024;
  const size_t SS = (size_t)4096 * 4096;
  unsigned short* qb = (unsigned short*)d_ws;
  unsigned short* kb = qb + SD;
  unsigned short* vt = kb + SD;            // v^T  [1024][16384]
  unsigned short* P0 = vt + SD;            // P slots [2][4096][4096]
  unsigned short* xb  = P0;                // aliased
  unsigned short* wqb = xb + SD;
  unsigned short* wkb = wqb + (size_t)1024 * 1024;
  unsigned short* wvb = wkb + (size_t)1024 * 1024;
  float* partial = (float*)(P0 + 2 * SS);  // [2][4096][64]
  float* rs = partial + (size_t)2 * 4096 * 64;

  cvt_f32_bf16<<<8192, 256, 0, stream>>>(x, xb);
  cvt_f32_bf16<<<512, 256, 0, stream>>>(Wq, wqb);
  cvt_f32_bf16<<<512, 256, 0, stream>>>(Wk, wkb);
  cvt_f32_bf16<<<512, 256, 0, stream>>>(Wv, wvb);

  // projections: [16384,1024] x [1024,1024]^T   (256 blocks, full fill)
  gemm256<0, 256><<<dim3(64, 4, 1), 512, 0, stream>>>(
      xb, 1024, 0, wqb, 1024, 0, qb, 1024, 0, bq, 0, 1024, 0.f, 0.f, nullptr);
  gemm256<0, 256><<<dim3(64, 4, 1), 512, 0, stream>>>(
      xb, 1024, 0, wkb, 1024, 0, kb, 1024, 0, bk, 0, 1024, 0.f, 0.f, nullptr);
  gemm256<1, 256><<<dim3(64, 4, 1), 512, 0, stream>>>(
      xb, 1024, 0, wvb, 1024, 0, vt, 16384, 0, bv, 0, 1024, 0.f, 0.f, nullptr);

  const float LOG2E = 1.4426950408889634f;
  const float c1 = LOG2E / 32.f;     // scores * (1/sqrt(D)) in log2 domain
  const float c2 = -16.f * LOG2E;    // fixed shift (softmax shift-invariant;
                                     // scores/32 ~ N(0,1) so e^(s-16) stays normal)
  for (int p = 0; p < 2; ++p) {      // batch pairs (b0,b0+1)
    const size_t qo = (size_t)p * 2 * 4096 * 1024;   // elem offset of batch pair
    // scores: P = exp2(q k^T * c1 + c2), z=2 -> 512 blocks
    gemm256<2, 256><<<dim3(16, 16, 2), 512, 0, stream>>>(
        qb + qo, 1024, SD / 4, kb + qo, 1024, SD / 4,
        P0, 4096, SS, nullptr, 0, 1024, c1, c2, partial);
    rs_recip<<<32, 256, 0, stream>>>(partial, rs);
    // PV: out = (P v) * rs, 128x256 tile, z=2 -> 256 blocks (full fill)
    gemm256<3, 128><<<dim3(32, 4, 2), 512, 0, stream>>>(
        P0, 4096, SS, vt + (size_t)p * 2 * 4096, 16384, 4096,
        out + qo, 1024, SD / 4, rs, 4096, 4096, 0.f, 0.f, nullptr);
  }
}